// Round 17
// baseline (60.806 us; speedup 1.0000x reference)
//
#include <hip/hip_runtime.h>

typedef __attribute__((ext_vector_type(8))) short short8;
typedef __attribute__((ext_vector_type(4))) float f32x4;

__device__ __forceinline__ unsigned short f2bf(float f) {
    unsigned u = __builtin_bit_cast(unsigned, f);
    unsigned r = (u + 0x7FFFu + ((u >> 16) & 1u)) >> 16;
    return (unsigned short)r;
}
__device__ __forceinline__ float bf2f(unsigned short u) {
    unsigned v = ((unsigned)u) << 16;
    return __builtin_bit_cast(float, v);
}

__device__ __forceinline__ void gload16(const unsigned short* g, unsigned short* l) {
    __builtin_amdgcn_global_load_lds(
        (const __attribute__((address_space(1))) void*)g,
        (__attribute__((address_space(3))) void*)l,
        16, 0, 0);
}

#define WAITV(N) asm volatile("s_waitcnt vmcnt(" #N ")" ::: "memory")
#define WAITL0() asm volatile("s_waitcnt lgkmcnt(0)" ::: "memory")
#define BAR() do { asm volatile("" ::: "memory"); __builtin_amdgcn_s_barrier(); asm volatile("" ::: "memory"); } while (0)

// ---- LDS tile swizzle: [128][32] bf16 tile (64B rows). 8-way -> <=2-way. ----
__device__ __forceinline__ short8 lds_read_swz(const unsigned short* tile, int row, int colb) {
    int off = row * 64 + colb;
    off ^= ((off >> 7) & 7) << 4;
    return *(const short8*)((const char*)tile + off);
}

// ---- XCD-aware 1D grid decode (T1): 8 y-blocks sharing a W panel get same id%8 ----
__device__ __forceinline__ void xcd_decode(int bid, int nxt, int& x, int& y, int& z) {
    int r = bid & 7, q = bid >> 3;
    y = q & 7;
    int p = (q >> 3) * 8 + r;      // p = x + nxt*z
    x = p % nxt; z = p / nxt;
}

// ---- fp32->bf16 one 8-elem chunk ----
__device__ __forceinline__ void cvt_chunk(const float* __restrict__ src,
                                          unsigned short* __restrict__ dst, int t) {
    const float4* s4 = (const float4*)src;
    float4 a = s4[2 * t], b = s4[2 * t + 1];
    union { unsigned short u[8]; int4 v; } r;
    r.u[0] = f2bf(a.x); r.u[1] = f2bf(a.y); r.u[2] = f2bf(a.z); r.u[3] = f2bf(a.w);
    r.u[4] = f2bf(b.x); r.u[5] = f2bf(b.y); r.u[6] = f2bf(b.z); r.u[7] = f2bf(b.w);
    ((int4*)dst)[t] = r.v;
}

__device__ __forceinline__ short8 pack8(float4 a, float4 b) {
    short8 p;
    p[0] = (short)f2bf(a.x); p[1] = (short)f2bf(a.y);
    p[2] = (short)f2bf(a.z); p[3] = (short)f2bf(a.w);
    p[4] = (short)f2bf(b.x); p[5] = (short)f2bf(b.y);
    p[6] = (short)f2bf(b.z); p[7] = (short)f2bf(b.w);
    return p;
}

// ======== layer-0 GEMM: fp32 reg-staged depth-3, LDS dbuf, 1 barrier/iter ========
// (R11/R14-validated, unchanged)
__global__ __launch_bounds__(512) void k_gemm0(
    const float* __restrict__ A, const float* __restrict__ W,
    const float* __restrict__ blend, const float* __restrict__ bias,
    unsigned short* __restrict__ Y,
    const float* __restrict__ csrc, unsigned short* __restrict__ cdst)
{
    __shared__ unsigned short As[2][4096];
    __shared__ unsigned short Bs[2][4096];

    int bx, by, e;
    xcd_decode(blockIdx.x, 4, bx, by, e);
    const int bm = by * 128;
    const int on = bx * 128;
    const int t  = threadIdx.x, lane = t & 63, w = t >> 6;
    const int wr = w >> 2, wc = w & 3;

    const int sr = lane >> 2, sce = (lane & 3) * 8;
    const int ra = w * 16 + sr;
    const float* gA = A + (size_t)(bm + ra) * 480 + sce;
    const float* gB = W + ((size_t)e * 512 + (on + ra)) * 480 + sce;

    int woff = ra * 64 + (lane & 3) * 16;
    woff ^= ((woff >> 7) & 7) << 4;

    float4 La0[3], La1[3], Lb0[3], Lb1[3];
    #pragma unroll
    for (int s = 0; s < 3; ++s) {
        int k0 = s * 32;
        La0[s] = *(const float4*)(gA + k0); La1[s] = *(const float4*)(gA + k0 + 4);
        Lb0[s] = *(const float4*)(gB + k0); Lb1[s] = *(const float4*)(gB + k0 + 4);
    }

    f32x4 acc[4][2] = {};

    #pragma unroll
    for (int kt = 0; kt < 15; ++kt) {
        const int s = kt % 3, buf = kt & 1;
        *(short8*)((char*)As[buf] + woff) = pack8(La0[s], La1[s]);
        *(short8*)((char*)Bs[buf] + woff) = pack8(Lb0[s], Lb1[s]);
        WAITL0();
        BAR();
        if (kt + 3 < 15) {
            int k0 = (kt + 3) * 32;
            La0[s] = *(const float4*)(gA + k0); La1[s] = *(const float4*)(gA + k0 + 4);
            Lb0[s] = *(const float4*)(gB + k0); Lb1[s] = *(const float4*)(gB + k0 + 4);
        }
        short8 af[4], bfr[2];
        #pragma unroll
        for (int fm = 0; fm < 4; ++fm)
            af[fm] = lds_read_swz(As[buf], wr * 64 + fm * 16 + (lane & 15), (lane >> 4) * 16);
        #pragma unroll
        for (int fn = 0; fn < 2; ++fn)
            bfr[fn] = lds_read_swz(Bs[buf], wc * 32 + fn * 16 + (lane & 15), (lane >> 4) * 16);
        #pragma unroll
        for (int fm = 0; fm < 4; ++fm)
            #pragma unroll
            for (int fn = 0; fn < 2; ++fn)
                acc[fm][fn] = __builtin_amdgcn_mfma_f32_16x16x32_bf16(
                    af[fm], bfr[fn], acc[fm][fn], 0, 0, 0);
    }

    const float* blendE = blend + e * 1024;
    const float* biasE  = bias + (size_t)e * 512;
    unsigned short* Ye  = Y + (size_t)e * 1024 * 512;
    #pragma unroll
    for (int fm = 0; fm < 4; ++fm) {
        int i0 = bm + wr * 64 + fm * 16 + (lane >> 4) * 4;
        float4 bl = *(const float4*)&blendE[i0];
        #pragma unroll
        for (int fn = 0; fn < 2; ++fn) {
            int j = on + wc * 32 + fn * 16 + (lane & 15);
            float bs = biasE[j];
            #pragma unroll
            for (int r = 0; r < 4; ++r)
                Ye[(size_t)(i0 + r) * 512 + j] = f2bf((acc[fm][fn][r] + bs) * ((&bl.x)[r]));
        }
    }

    int lb = (e * 8 + by) * 4 + bx;
    cvt_chunk(csrc, cdst, lb * 1024 + threadIdx.x);
    cvt_chunk(csrc, cdst, lb * 1024 + 512 + threadIdx.x);
}

// ======== layers 1/2: bf16, K=512, depth-4 gload16, 1 barrier/iter (R14) ========
// fout==nullptr: write blend/bias-scaled bf16 planes (middle layer).
// fout!=nullptr: FINAL layer — fp32 atomicAdd of blend*(acc+bias) into out[1024][311]
//                (linear, no activation), no plane writes.
// zdst: optional zero-fill tail (G1 zeroes d_out for G2's atomics; no extra dispatch).
__global__ __launch_bounds__(512) void k_gemm(
    const unsigned short* __restrict__ A,
    const unsigned short* __restrict__ W,
    const float* __restrict__ blend, const float* __restrict__ bias,
    unsigned short* __restrict__ Y, float* __restrict__ fout,
    int N, int ldy, int nxt,
    const float* __restrict__ csrc, unsigned short* __restrict__ cdst, int nchunk,
    float4* __restrict__ zdst, int nz4)
{
    __shared__ unsigned short As[4][4096];   // 32 KB
    __shared__ unsigned short Bs[4][4096];   // 32 KB

    int bx, by, e;
    xcd_decode(blockIdx.x, nxt, bx, by, e);
    const int bm = by * 128;
    const int on = bx * 128;
    const int t  = threadIdx.x, lane = t & 63, w = t >> 6;
    const int wr = w >> 2, wc = w & 3;

    const unsigned short* Wt = W + (size_t)e * N * 512;
    // pre-swizzled source lane (rule #21): linear gload dest + permuted global src
    const int l2 = lane ^ ((lane >> 3) & 7);
    const int sr = l2 >> 2, sce = (l2 & 3) * 8;
    const int ra = w * 16 + sr;
    int rb = on + ra; if (rb > N - 1) rb = N - 1;
    const unsigned short* gA = A  + (size_t)(bm + ra) * 512 + sce;
    const unsigned short* gB = Wt + (size_t)rb * 512 + sce;

#define STAGE(buf, kt) do { int _k0 = (kt) * 32;                       \
        gload16(gA + _k0, &As[(buf)][w * 512]);                        \
        gload16(gB + _k0, &Bs[(buf)][w * 512]); } while (0)

#define COMPUTE(cur) do {                                                          \
        short8 af[4], bfr[2];                                                      \
        _Pragma("unroll")                                                          \
        for (int fm = 0; fm < 4; ++fm)                                             \
            af[fm] = lds_read_swz(As[(cur)], wr * 64 + fm * 16 + (lane & 15), (lane >> 4) * 16); \
        _Pragma("unroll")                                                          \
        for (int fn = 0; fn < 2; ++fn)                                             \
            bfr[fn] = lds_read_swz(Bs[(cur)], wc * 32 + fn * 16 + (lane & 15), (lane >> 4) * 16); \
        _Pragma("unroll")                                                          \
        for (int fm = 0; fm < 4; ++fm)                                             \
            _Pragma("unroll")                                                      \
            for (int fn = 0; fn < 2; ++fn)                                         \
                acc[fm][fn] = __builtin_amdgcn_mfma_f32_16x16x32_bf16(             \
                    af[fm], bfr[fn], acc[fm][fn], 0, 0, 0);                        \
    } while (0)

    f32x4 acc[4][2] = {};
    STAGE(0, 0); STAGE(1, 1); STAGE(2, 2);   // 6 loads in flight / thread

    for (int kt = 0; kt < 13; ++kt) {
        WAITV(4);
        BAR();                                // tile kt in LDS; tile kt-1 reads done
        STAGE((kt + 3) & 3, kt + 3);          // overwrite tile kt-1's buffer
        COMPUTE(kt & 3);
    }
    WAITV(4); BAR(); COMPUTE(1);
    WAITV(2); BAR(); COMPUTE(2);
    WAITV(0); BAR(); COMPUTE(3);
#undef STAGE

    const float* blendE = blend + e * 1024;
    const float* biasE  = bias + (size_t)e * N;
    if (fout) {
        // final layer: out[i][j] += blend_e[i] * (acc + bias_e[j]); fp32 atomics
        #pragma unroll
        for (int fm = 0; fm < 4; ++fm) {
            int i0 = bm + wr * 64 + fm * 16 + (lane >> 4) * 4;
            float4 bl = *(const float4*)&blendE[i0];
            #pragma unroll
            for (int fn = 0; fn < 2; ++fn) {
                int j = on + wc * 32 + fn * 16 + (lane & 15);
                if (j < N) {
                    float bs = biasE[j];
                    #pragma unroll
                    for (int r = 0; r < 4; ++r)
                        atomicAdd(&fout[(size_t)(i0 + r) * 311 + j],
                                  (acc[fm][fn][r] + bs) * ((&bl.x)[r]));
                }
            }
        }
    } else {
        unsigned short* Ye = Y + (size_t)e * 1024 * ldy;
        #pragma unroll
        for (int fm = 0; fm < 4; ++fm) {
            int i0 = bm + wr * 64 + fm * 16 + (lane >> 4) * 4;
            float4 bl = *(const float4*)&blendE[i0];
            #pragma unroll
            for (int fn = 0; fn < 2; ++fn) {
                int j = on + wc * 32 + fn * 16 + (lane & 15);
                if (j < N) {
                    float bs = biasE[j];
                    #pragma unroll
                    for (int r = 0; r < 4; ++r)
                        Ye[(size_t)(i0 + r) * ldy + j] = f2bf((acc[fm][fn][r] + bs) * ((&bl.x)[r]));
                }
            }
        }
    }

    if (cdst) {
        int lb = (e * 8 + by) * nxt + bx;
        #pragma unroll
        for (int q = 0; q < 2; ++q) {
            int tl = q * 512 + threadIdx.x;
            if (tl < nchunk) cvt_chunk(csrc, cdst, lb * nchunk + tl);
        }
    }
    if (zdst) {                               // zero-fill tail (hidden under stragglers)
        int gid = blockIdx.x * 512 + threadIdx.x;
        float4 z; z.x = 0.f; z.y = 0.f; z.z = 0.f; z.w = 0.f;
        for (int i = gid; i < nz4; i += 131072) zdst[i] = z;
    }
}

// ---- sum 8 bf16 planes + ELU -> bf16 (N=512), 8 elems/thread ----
__global__ __launch_bounds__(256) void k_reduce8(
    const unsigned short* __restrict__ Y, unsigned short* __restrict__ out)
{
    int idx = blockIdx.x * 256 + threadIdx.x;
    int b  = idx >> 6;
    int o0 = (idx & 63) * 8;
    size_t base = (size_t)b * 512 + o0;
    float s[8] = {};
    #pragma unroll
    for (int p = 0; p < 8; ++p) {
        int4 v = *(const int4*)&Y[base + (size_t)p * 1024 * 512];
        const unsigned short* u = (const unsigned short*)&v;
        #pragma unroll
        for (int r = 0; r < 8; ++r) s[r] += bf2f(u[r]);
    }
    union { unsigned short u[8]; int4 v; } rr;
    #pragma unroll
    for (int r = 0; r < 8; ++r) {
        float v = (s[r] > 0.f) ? s[r] : expm1f(s[r]);
        rr.u[r] = f2bf(v);
    }
    *(int4*)&out[base] = rr.v;
}

extern "C" void kernel_launch(void* const* d_in, const int* in_sizes, int n_in,
                              void* d_out, int out_size, void* d_ws, size_t ws_size,
                              hipStream_t stream) {
    const float* x     = (const float*)d_in[0];
    const float* blend = (const float*)d_in[1];
    const float* w0    = (const float*)d_in[2];
    const float* b0    = (const float*)d_in[3];
    const float* w1    = (const float*)d_in[4];
    const float* b1    = (const float*)d_in[5];
    const float* w2    = (const float*)d_in[6];
    const float* b2    = (const float*)d_in[7];

    char* ws = (char*)d_ws;
    unsigned short* w1b = (unsigned short*)(ws + 0);         // 4,194,304
    unsigned short* w2b = (unsigned short*)(ws + 4194304);   // 2,547,712
    unsigned short* h1b = (unsigned short*)(ws + 6742016);   // 1,048,576
    unsigned short* h2b = (unsigned short*)(ws + 7790592);   // 1,048,576
    unsigned short* yb  = (unsigned short*)(ws + 8839168);   // 8,388,608 (8 bf16 planes)

    // L0: fp32-direct GEMM -> yb planes, + tail-convert w1
    k_gemm0<<<256, 512, 0, stream>>>(x, w0, blend, b0, yb, w1, w1b);
    k_reduce8<<<256, 256, 0, stream>>>(yb, h1b);

    // L1: bf16 GEMM -> yb planes, + tail-convert w2, + tail-zero d_out (for L2 atomics)
    k_gemm<<<256, 512, 0, stream>>>(h1b, w1b, blend, b1, yb, nullptr, 512, 512, 4,
                                    w2, w2b, 622, (float4*)d_out, 79616);
    k_reduce8<<<256, 256, 0, stream>>>(yb, h2b);

    // L2 (final, linear): fp32 atomicAdd directly into d_out — no reduce dispatch
    k_gemm<<<192, 512, 0, stream>>>(h2b, w2b, blend, b2, yb, (float*)d_out, 311, 320, 3,
                                    nullptr, nullptr, 0, nullptr, 0);
}

// Round 18
// 53.202 us; speedup vs baseline: 1.1429x; 1.1429x over previous
//
#include <hip/hip_runtime.h>

typedef __attribute__((ext_vector_type(8))) short short8;
typedef __attribute__((ext_vector_type(4))) float f32x4;

__device__ __forceinline__ unsigned short f2bf(float f) {
    unsigned u = __builtin_bit_cast(unsigned, f);
    unsigned r = (u + 0x7FFFu + ((u >> 16) & 1u)) >> 16;
    return (unsigned short)r;
}
__device__ __forceinline__ float bf2f(unsigned short u) {
    unsigned v = ((unsigned)u) << 16;
    return __builtin_bit_cast(float, v);
}

__device__ __forceinline__ void gload16(const unsigned short* g, unsigned short* l) {
    __builtin_amdgcn_global_load_lds(
        (const __attribute__((address_space(1))) void*)g,
        (__attribute__((address_space(3))) void*)l,
        16, 0, 0);
}

#define WAITV(N) asm volatile("s_waitcnt vmcnt(" #N ")" ::: "memory")
#define WAITL0() asm volatile("s_waitcnt lgkmcnt(0)" ::: "memory")
#define BAR() do { asm volatile("" ::: "memory"); __builtin_amdgcn_s_barrier(); asm volatile("" ::: "memory"); } while (0)

// ---- LDS tile swizzle: [128][32] bf16 tile (64B rows). 8-way -> <=2-way. ----
__device__ __forceinline__ short8 lds_read_swz(const unsigned short* tile, int row, int colb) {
    int off = row * 64 + colb;
    off ^= ((off >> 7) & 7) << 4;
    return *(const short8*)((const char*)tile + off);
}

// ---- XCD-aware 1D grid decode (T1): 8 y-blocks sharing a W panel get same id%8 ----
__device__ __forceinline__ void xcd_decode(int bid, int nxt, int& x, int& y, int& z) {
    int r = bid & 7, q = bid >> 3;
    y = q & 7;
    int p = (q >> 3) * 8 + r;      // p = x + nxt*z
    x = p % nxt; z = p / nxt;
}

// ---- fp32->bf16 one 8-elem chunk ----
__device__ __forceinline__ void cvt_chunk(const float* __restrict__ src,
                                          unsigned short* __restrict__ dst, int t) {
    const float4* s4 = (const float4*)src;
    float4 a = s4[2 * t], b = s4[2 * t + 1];
    union { unsigned short u[8]; int4 v; } r;
    r.u[0] = f2bf(a.x); r.u[1] = f2bf(a.y); r.u[2] = f2bf(a.z); r.u[3] = f2bf(a.w);
    r.u[4] = f2bf(b.x); r.u[5] = f2bf(b.y); r.u[6] = f2bf(b.z); r.u[7] = f2bf(b.w);
    ((int4*)dst)[t] = r.v;
}

__device__ __forceinline__ short8 pack8(float4 a, float4 b) {
    short8 p;
    p[0] = (short)f2bf(a.x); p[1] = (short)f2bf(a.y);
    p[2] = (short)f2bf(a.z); p[3] = (short)f2bf(a.w);
    p[4] = (short)f2bf(b.x); p[5] = (short)f2bf(b.y);
    p[6] = (short)f2bf(b.z); p[7] = (short)f2bf(b.w);
    return p;
}

// ======== layer-0 GEMM: fp32 reg-staged depth-3, LDS dbuf, 1 barrier/iter ========
__global__ __launch_bounds__(512) void k_gemm0(
    const float* __restrict__ A, const float* __restrict__ W,
    const float* __restrict__ blend, const float* __restrict__ bias,
    unsigned short* __restrict__ Y,
    const float* __restrict__ csrc, unsigned short* __restrict__ cdst)
{
    __shared__ unsigned short As[2][4096];
    __shared__ unsigned short Bs[2][4096];

    int bx, by, e;
    xcd_decode(blockIdx.x, 4, bx, by, e);
    const int bm = by * 128;
    const int on = bx * 128;
    const int t  = threadIdx.x, lane = t & 63, w = t >> 6;
    const int wr = w >> 2, wc = w & 3;

    const int sr = lane >> 2, sce = (lane & 3) * 8;
    const int ra = w * 16 + sr;
    const float* gA = A + (size_t)(bm + ra) * 480 + sce;
    const float* gB = W + ((size_t)e * 512 + (on + ra)) * 480 + sce;

    int woff = ra * 64 + (lane & 3) * 16;
    woff ^= ((woff >> 7) & 7) << 4;

    float4 La0[3], La1[3], Lb0[3], Lb1[3];
    #pragma unroll
    for (int s = 0; s < 3; ++s) {
        int k0 = s * 32;
        La0[s] = *(const float4*)(gA + k0); La1[s] = *(const float4*)(gA + k0 + 4);
        Lb0[s] = *(const float4*)(gB + k0); Lb1[s] = *(const float4*)(gB + k0 + 4);
    }

    f32x4 acc[4][2] = {};

    #pragma unroll
    for (int kt = 0; kt < 15; ++kt) {
        const int s = kt % 3, buf = kt & 1;
        *(short8*)((char*)As[buf] + woff) = pack8(La0[s], La1[s]);
        *(short8*)((char*)Bs[buf] + woff) = pack8(Lb0[s], Lb1[s]);
        WAITL0();
        BAR();
        if (kt + 3 < 15) {
            int k0 = (kt + 3) * 32;
            La0[s] = *(const float4*)(gA + k0); La1[s] = *(const float4*)(gA + k0 + 4);
            Lb0[s] = *(const float4*)(gB + k0); Lb1[s] = *(const float4*)(gB + k0 + 4);
        }
        short8 af[4], bfr[2];
        #pragma unroll
        for (int fm = 0; fm < 4; ++fm)
            af[fm] = lds_read_swz(As[buf], wr * 64 + fm * 16 + (lane & 15), (lane >> 4) * 16);
        #pragma unroll
        for (int fn = 0; fn < 2; ++fn)
            bfr[fn] = lds_read_swz(Bs[buf], wc * 32 + fn * 16 + (lane & 15), (lane >> 4) * 16);
        #pragma unroll
        for (int fm = 0; fm < 4; ++fm)
            #pragma unroll
            for (int fn = 0; fn < 2; ++fn)
                acc[fm][fn] = __builtin_amdgcn_mfma_f32_16x16x32_bf16(
                    af[fm], bfr[fn], acc[fm][fn], 0, 0, 0);
    }

    const float* blendE = blend + e * 1024;
    const float* biasE  = bias + (size_t)e * 512;
    unsigned short* Ye  = Y + (size_t)e * 1024 * 512;
    #pragma unroll
    for (int fm = 0; fm < 4; ++fm) {
        int i0 = bm + wr * 64 + fm * 16 + (lane >> 4) * 4;
        float4 bl = *(const float4*)&blendE[i0];
        #pragma unroll
        for (int fn = 0; fn < 2; ++fn) {
            int j = on + wc * 32 + fn * 16 + (lane & 15);
            float bs = biasE[j];
            #pragma unroll
            for (int r = 0; r < 4; ++r)
                Ye[(size_t)(i0 + r) * 512 + j] = f2bf((acc[fm][fn][r] + bs) * ((&bl.x)[r]));
        }
    }

    int lb = (e * 8 + by) * 4 + bx;
    cvt_chunk(csrc, cdst, lb * 1024 + threadIdx.x);
    cvt_chunk(csrc, cdst, lb * 1024 + 512 + threadIdx.x);
}

// ======== layers 1/2: bf16, K=512, depth-4 gload16, 1 barrier/iter (R11) ========
__global__ __launch_bounds__(512) void k_gemm(
    const unsigned short* __restrict__ A,
    const unsigned short* __restrict__ W,
    const float* __restrict__ blend, const float* __restrict__ bias,
    unsigned short* __restrict__ Y,
    int N, int ldy, int nxt,
    const float* __restrict__ csrc, unsigned short* __restrict__ cdst, int nchunk)
{
    __shared__ unsigned short As[4][4096];   // 32 KB
    __shared__ unsigned short Bs[4][4096];   // 32 KB

    int bx, by, e;
    xcd_decode(blockIdx.x, nxt, bx, by, e);
    const int bm = by * 128;
    const int on = bx * 128;
    const int t  = threadIdx.x, lane = t & 63, w = t >> 6;
    const int wr = w >> 2, wc = w & 3;

    const unsigned short* Wt = W + (size_t)e * N * 512;
    // pre-swizzled source lane (rule #21): linear gload dest + permuted global src
    const int l2 = lane ^ ((lane >> 3) & 7);
    const int sr = l2 >> 2, sce = (l2 & 3) * 8;
    const int ra = w * 16 + sr;
    int rb = on + ra; if (rb > N - 1) rb = N - 1;
    const unsigned short* gA = A  + (size_t)(bm + ra) * 512 + sce;
    const unsigned short* gB = Wt + (size_t)rb * 512 + sce;

#define STAGE(buf, kt) do { int _k0 = (kt) * 32;                       \
        gload16(gA + _k0, &As[(buf)][w * 512]);                        \
        gload16(gB + _k0, &Bs[(buf)][w * 512]); } while (0)

#define COMPUTE(cur) do {                                                          \
        short8 af[4], bfr[2];                                                      \
        _Pragma("unroll")                                                          \
        for (int fm = 0; fm < 4; ++fm)                                             \
            af[fm] = lds_read_swz(As[(cur)], wr * 64 + fm * 16 + (lane & 15), (lane >> 4) * 16); \
        _Pragma("unroll")                                                          \
        for (int fn = 0; fn < 2; ++fn)                                             \
            bfr[fn] = lds_read_swz(Bs[(cur)], wc * 32 + fn * 16 + (lane & 15), (lane >> 4) * 16); \
        _Pragma("unroll")                                                          \
        for (int fm = 0; fm < 4; ++fm)                                             \
            _Pragma("unroll")                                                      \
            for (int fn = 0; fn < 2; ++fn)                                         \
                acc[fm][fn] = __builtin_amdgcn_mfma_f32_16x16x32_bf16(             \
                    af[fm], bfr[fn], acc[fm][fn], 0, 0, 0);                        \
    } while (0)

    f32x4 acc[4][2] = {};
    STAGE(0, 0); STAGE(1, 1); STAGE(2, 2);   // 6 loads in flight / thread

    for (int kt = 0; kt < 13; ++kt) {
        WAITV(4);
        BAR();                                // tile kt in LDS; tile kt-1 reads done
        STAGE((kt + 3) & 3, kt + 3);          // overwrite tile kt-1's buffer
        COMPUTE(kt & 3);
    }
    WAITV(4); BAR(); COMPUTE(1);
    WAITV(2); BAR(); COMPUTE(2);
    WAITV(0); BAR(); COMPUTE(3);
#undef STAGE

    const float* blendE = blend + e * 1024;
    const float* biasE  = bias + (size_t)e * N;
    unsigned short* Ye  = Y + (size_t)e * 1024 * ldy;
    #pragma unroll
    for (int fm = 0; fm < 4; ++fm) {
        int i0 = bm + wr * 64 + fm * 16 + (lane >> 4) * 4;
        float4 bl = *(const float4*)&blendE[i0];
        #pragma unroll
        for (int fn = 0; fn < 2; ++fn) {
            int j = on + wc * 32 + fn * 16 + (lane & 15);
            if (j < N) {
                float bs = biasE[j];
                #pragma unroll
                for (int r = 0; r < 4; ++r)
                    Ye[(size_t)(i0 + r) * ldy + j] = f2bf((acc[fm][fn][r] + bs) * ((&bl.x)[r]));
            }
        }
    }

    if (cdst) {
        int lb = (e * 8 + by) * nxt + bx;
        #pragma unroll
        for (int q = 0; q < 2; ++q) {
            int tl = q * 512 + threadIdx.x;
            if (tl < nchunk) cvt_chunk(csrc, cdst, lb * nchunk + tl);
        }
    }
}

// ---- sum 8 bf16 planes + ELU -> bf16 (N=512), 8 elems/thread ----
__global__ __launch_bounds__(256) void k_reduce8(
    const unsigned short* __restrict__ Y, unsigned short* __restrict__ out)
{
    int idx = blockIdx.x * 256 + threadIdx.x;
    int b  = idx >> 6;
    int o0 = (idx & 63) * 8;
    size_t base = (size_t)b * 512 + o0;
    float s[8] = {};
    #pragma unroll
    for (int p = 0; p < 8; ++p) {
        int4 v = *(const int4*)&Y[base + (size_t)p * 1024 * 512];
        const unsigned short* u = (const unsigned short*)&v;
        #pragma unroll
        for (int r = 0; r < 8; ++r) s[r] += bf2f(u[r]);
    }
    union { unsigned short u[8]; int4 v; } rr;
    #pragma unroll
    for (int r = 0; r < 8; ++r) {
        float v = (s[r] > 0.f) ? s[r] : expm1f(s[r]);
        rr.u[r] = f2bf(v);
    }
    *(int4*)&out[base] = rr.v;
}

// ---- final: sum 8 planes (ldy=320), fp32 out, N=311 ----
__global__ __launch_bounds__(256) void k_reduce_last(
    const unsigned short* __restrict__ Y, float* __restrict__ out)
{
    int idx = blockIdx.x * 256 + threadIdx.x;
    if (idx >= 1024 * 40) return;
    int b  = idx / 40;
    int o0 = (idx - b * 40) * 8;
    size_t base = (size_t)b * 320 + o0;
    float s[8] = {};
    #pragma unroll
    for (int p = 0; p < 8; ++p) {
        int4 v = *(const int4*)&Y[base + (size_t)p * 1024 * 320];
        const unsigned short* u = (const unsigned short*)&v;
        #pragma unroll
        for (int r = 0; r < 8; ++r) s[r] += bf2f(u[r]);
    }
    #pragma unroll
    for (int r = 0; r < 8; ++r)
        if (o0 + r < 311) out[(size_t)b * 311 + o0 + r] = s[r];
}

extern "C" void kernel_launch(void* const* d_in, const int* in_sizes, int n_in,
                              void* d_out, int out_size, void* d_ws, size_t ws_size,
                              hipStream_t stream) {
    const float* x     = (const float*)d_in[0];
    const float* blend = (const float*)d_in[1];
    const float* w0    = (const float*)d_in[2];
    const float* b0    = (const float*)d_in[3];
    const float* w1    = (const float*)d_in[4];
    const float* b1    = (const float*)d_in[5];
    const float* w2    = (const float*)d_in[6];
    const float* b2    = (const float*)d_in[7];

    char* ws = (char*)d_ws;
    unsigned short* w1b = (unsigned short*)(ws + 0);         // 4,194,304
    unsigned short* w2b = (unsigned short*)(ws + 4194304);   // 2,547,712
    unsigned short* h1b = (unsigned short*)(ws + 6742016);   // 1,048,576
    unsigned short* h2b = (unsigned short*)(ws + 7790592);   // 1,048,576
    unsigned short* yb  = (unsigned short*)(ws + 8839168);   // 8,388,608 (8 bf16 planes)

    // layer 0: fp32-direct GEMM + tail-convert w1 (XCD-swizzled 1D grid)
    k_gemm0<<<256, 512, 0, stream>>>(x, w0, blend, b0, yb, w1, w1b);
    k_reduce8<<<256, 256, 0, stream>>>(yb, h1b);

    // layer 1: bf16 GEMM + tail-convert w2
    k_gemm<<<256, 512, 0, stream>>>(h1b, w1b, blend, b1, yb, 512, 512, 4,
                                    w2, w2b, 622);
    k_reduce8<<<256, 256, 0, stream>>>(yb, h2b);

    // layer 2: bf16 GEMM, N=311 (ldy=320)
    k_gemm<<<192, 512, 0, stream>>>(h2b, w2b, blend, b2, yb, 311, 320, 3,
                                    nullptr, nullptr, 0);
    k_reduce_last<<<160, 256, 0, stream>>>(yb, (float*)d_out);
}